// Round 6
// baseline (174.756 us; speedup 1.0000x reference)
//
#include <hip/hip_runtime.h>
#include <hip/hip_bf16.h>
#include <hip/hip_fp16.h>

#define N_NODES 50000
#define N_EDGES 800000
#define HEADS 4
#define OUT_CH 32
#define FDIM (HEADS * OUT_CH)   // 128

typedef float vfloat4 __attribute__((ext_vector_type(4)));

// ============================================================================
// CSR-build helpers
// ============================================================================

__global__ void hist_kernel(const int* __restrict__ ei, int* __restrict__ cnt,
                            int n_edges) {
    int e = blockIdx.x * blockDim.x + threadIdx.x;
    if (e < n_edges) atomicAdd(&cnt[ei[e]], 1);
}

__global__ void scan1_kernel(const int* __restrict__ cnt, int* __restrict__ offs,
                             int* __restrict__ bsums, int n) {
    __shared__ int lds[256];
    int i = blockIdx.x * 256 + threadIdx.x;
    int v = (i < n) ? cnt[i] : 0;
    lds[threadIdx.x] = v;
    __syncthreads();
    for (int d = 1; d < 256; d <<= 1) {
        int t = (threadIdx.x >= d) ? lds[threadIdx.x - d] : 0;
        __syncthreads();
        lds[threadIdx.x] += t;
        __syncthreads();
    }
    if (i < n) offs[i] = lds[threadIdx.x] - v;
    if (threadIdx.x == 255) bsums[blockIdx.x] = lds[255];
}

__global__ void scan2_kernel(int* __restrict__ bsums, int* __restrict__ offs_n,
                             int nb) {
    __shared__ int lds[256];
    int v = (threadIdx.x < nb) ? bsums[threadIdx.x] : 0;
    lds[threadIdx.x] = v;
    __syncthreads();
    for (int d = 1; d < 256; d <<= 1) {
        int t = (threadIdx.x >= d) ? lds[threadIdx.x - d] : 0;
        __syncthreads();
        lds[threadIdx.x] += t;
        __syncthreads();
    }
    if (threadIdx.x < nb) bsums[threadIdx.x] = lds[threadIdx.x] - v;
    if (threadIdx.x == 255) *offs_n = lds[255];
}

__global__ void scan3_kernel(int* __restrict__ offs, int* __restrict__ cursor,
                             const int* __restrict__ bsums, int n) {
    int i = blockIdx.x * 256 + threadIdx.x;
    if (i < n) {
        int o = offs[i] + bsums[blockIdx.x];
        offs[i] = o;
        cursor[i] = o;
    }
}

// ============================================================================
// v6 path: perm-only CSR (4B scattered footprint), beta fused into gather
// ============================================================================

// Fused: A/B node dots + x -> fp16 conversion. 32 threads/node.
__global__ void prep_kernel(const float4* __restrict__ x4,
                            const float* __restrict__ w,
                            float* __restrict__ Af,
                            float* __restrict__ Bf,
                            ushort4* __restrict__ xh4) {
    int gid = blockIdx.x * blockDim.x + threadIdx.x;
    int node = gid >> 5;
    int t = threadIdx.x & 31;
    int h = t >> 3;
    int q8 = t & 7;

    float4 xv = x4[node * 32 + t];

    ushort4 u;
    u.x = __half_as_ushort(__float2half(xv.x));
    u.y = __half_as_ushort(__float2half(xv.y));
    u.z = __half_as_ushort(__float2half(xv.z));
    u.w = __half_as_ushort(__float2half(xv.w));
    xh4[node * 32 + t] = u;

    const float4* w4 = (const float4*)w;
    float4 wi = w4[q8];
    float4 wj = w4[8 + q8];
    float pa = xv.x * wi.x + xv.y * wi.y + xv.z * wi.z + xv.w * wi.w;
    float pb = xv.x * wj.x + xv.y * wj.y + xv.z * wj.z + xv.w * wj.w;
    #pragma unroll
    for (int m = 4; m >= 1; m >>= 1) {
        pa += __shfl_xor(pa, m);
        pb += __shfl_xor(pb, m);
    }
    if (q8 == 0) {
        Af[node * 4 + h] = pa;
        Bf[node * 4 + h] = pb;
    }
}

// permutation scatter: only 4B per edge lands in a random location.
// 2 edges/thread for ILP while keeping wave count high.
__global__ void perm_kernel(const int* __restrict__ ei,
                            int* __restrict__ cursor,
                            int* __restrict__ perm,
                            int n_edges) {
    int base = blockIdx.x * (blockDim.x * 2) + threadIdx.x;
    #pragma unroll
    for (int u = 0; u < 2; ++u) {
        int e = base + u * 256;
        if (e < n_edges) {
            int i = ei[e];
            int p = atomicAdd(&cursor[i], 1);
            perm[p] = e;
        }
    }
}

// gather: 32 threads/node; beta recomputed in-register from L2-resident tables.
__global__ void gather_fused_kernel(const ushort4* __restrict__ xh4,
                                    const float* __restrict__ Af,
                                    const float* __restrict__ Bf,
                                    const int* __restrict__ ej,
                                    const float* __restrict__ weights,
                                    const int* __restrict__ offs,
                                    const int* __restrict__ perm,
                                    float4* __restrict__ out4) {
    int gid = blockIdx.x * blockDim.x + threadIdx.x;
    int node = gid >> 5;
    int t = threadIdx.x & 31;
    int h = t >> 3;

    int start = offs[node];
    int end = offs[node + 1];
    float a_h = Af[node * 4 + h];
    float4 acc = make_float4(0.f, 0.f, 0.f, 0.f);
    #pragma unroll 4
    for (int k = start; k < end; ++k) {
        int e = perm[k];
        int j = ej[e];
        float we = weights[e];
        float b_h = Bf[j * 4 + h];
        float beta = we / (1.0f + __expf(-(a_h + b_h)));
        ushort4 xv = xh4[j * 32 + t];
        acc.x += __half2float(__ushort_as_half(xv.x)) * beta;
        acc.y += __half2float(__ushort_as_half(xv.y)) * beta;
        acc.z += __half2float(__ushort_as_half(xv.z)) * beta;
        acc.w += __half2float(__ushort_as_half(xv.w)) * beta;
    }
    // streaming store: out is never re-read, keep it out of L2
    vfloat4 av; av.x = acc.x; av.y = acc.y; av.z = acc.z; av.w = acc.w;
    __builtin_nontemporal_store(av, (vfloat4*)&out4[node * 32 + t]);
}

// ============================================================================
// v0 ultimate fallback: atomic scatter (tiny workspace)
// ============================================================================

__global__ void node_dots_kernel(const float* __restrict__ x,
                                 const float* __restrict__ w,
                                 float* __restrict__ ab,
                                 int n_nodes) {
    int gid = blockIdx.x * blockDim.x + threadIdx.x;
    int node = gid >> 7;
    int t = threadIdx.x & 127;
    if (node >= n_nodes) return;
    int h = t >> 5;
    int c = t & 31;
    float xv = x[node * FDIM + t];
    float pa = xv * w[c];
    float pb = xv * w[OUT_CH + c];
    #pragma unroll
    for (int m = 16; m >= 1; m >>= 1) {
        pa += __shfl_xor(pa, m);
        pb += __shfl_xor(pb, m);
    }
    if (c == 0) {
        ab[node * 8 + h * 2 + 0] = pa;
        ab[node * 8 + h * 2 + 1] = pb;
    }
}

__global__ void edge_scatter_kernel(const float* __restrict__ x,
                                    const int* __restrict__ ei_arr,
                                    const int* __restrict__ ej_arr,
                                    const float* __restrict__ weights,
                                    const float* __restrict__ ab,
                                    float* __restrict__ out,
                                    int n_edges) {
    int gid = blockIdx.x * blockDim.x + threadIdx.x;
    int e = gid >> 7;
    int t = threadIdx.x & 127;
    if (e >= n_edges) return;
    int h = t >> 5;
    int i = ei_arr[e];
    int j = ej_arr[e];
    float alpha = ab[i * 8 + h * 2 + 0] + ab[j * 8 + h * 2 + 1];
    float beta = weights[e] / (1.0f + __expf(-alpha));
    atomicAdd(&out[i * FDIM + t], x[j * FDIM + t] * beta);
}

// ============================================================================

extern "C" void kernel_launch(void* const* d_in, const int* in_sizes, int n_in,
                              void* d_out, int out_size, void* d_ws, size_t ws_size,
                              hipStream_t stream) {
    const float* x       = (const float*)d_in[0];
    const int*   eidx    = (const int*)d_in[1];
    const float* weights = (const float*)d_in[2];
    const float* w       = (const float*)d_in[3];
    float* out = (float*)d_out;

    const int* ei_arr = eidx;
    const int* ej_arr = eidx + N_EDGES;

    const int NB = (N_NODES + 255) / 256;  // scan blocks (196)

    // ---- v6 workspace layout ----
    // xh: 12.8MB | A: 800KB | B: 800KB | perm: 3.2MB |
    // cnt: 200KB | offs: 200KB+4 | cursor: 200KB | bsums: 1KB  => ~18.2MB
    {
        char* p = (char*)d_ws;
        ushort4* xh4  = (ushort4*)p;   p += (size_t)N_NODES * FDIM * 2;
        float*   Af   = (float*)p;     p += (size_t)N_NODES * 4 * 4;
        float*   Bf   = (float*)p;     p += (size_t)N_NODES * 4 * 4;
        int*     perm = (int*)p;       p += (size_t)N_EDGES * 4;
        int*     cnt  = (int*)p;       p += (size_t)N_NODES * 4;
        int*     offs = (int*)p;       p += (size_t)(N_NODES + 1) * 4;
        int*     cur  = (int*)p;       p += (size_t)N_NODES * 4;
        int*     bsums= (int*)p;       p += (size_t)256 * 4;
        size_t need_v6 = (size_t)(p - (char*)d_ws);

        if (ws_size >= need_v6) {
            hipMemsetAsync(cnt, 0, (size_t)N_NODES * sizeof(int), stream);
            prep_kernel<<<(N_NODES * 32) / 256, 256, 0, stream>>>(
                (const float4*)x, w, Af, Bf, xh4);
            hist_kernel<<<(N_EDGES + 255) / 256, 256, 0, stream>>>(
                ei_arr, cnt, N_EDGES);
            scan1_kernel<<<NB, 256, 0, stream>>>(cnt, offs, bsums, N_NODES);
            scan2_kernel<<<1, 256, 0, stream>>>(bsums, offs + N_NODES, NB);
            scan3_kernel<<<NB, 256, 0, stream>>>(offs, cur, bsums, N_NODES);
            perm_kernel<<<(N_EDGES + 511) / 512, 256, 0, stream>>>(
                ei_arr, cur, perm, N_EDGES);
            gather_fused_kernel<<<(N_NODES * 32) / 256, 256, 0, stream>>>(
                xh4, Af, Bf, ej_arr, weights, offs, perm, (float4*)out);
            return;
        }
    }

    // ---- v0 atomic fallback ----
    {
        float* ab = (float*)d_ws;  // 1.6MB
        int grid = (N_NODES * FDIM + 255) / 256;
        node_dots_kernel<<<grid, 256, 0, stream>>>(x, w, ab, N_NODES);
        hipMemsetAsync(d_out, 0, (size_t)out_size * sizeof(float), stream);
        long long threads_total = (long long)N_EDGES * FDIM;
        long long g = (threads_total + 255) / 256;
        edge_scatter_kernel<<<(int)g, 256, 0, stream>>>(
            x, ei_arr, ej_arr, weights, ab, out, N_EDGES);
    }
}

// Round 7
// 121.267 us; speedup vs baseline: 1.4411x; 1.4411x over previous
//
#include <hip/hip_runtime.h>
#include <hip/hip_bf16.h>
#include <hip/hip_fp16.h>

#define N_NODES 50000
#define N_EDGES 800000
#define HEADS 4
#define OUT_CH 32
#define FDIM (HEADS * OUT_CH)   // 128

typedef float vfloat4 __attribute__((ext_vector_type(4)));

// ============================================================================
// common: prep (A/B dots + fp16 x-table)
// ============================================================================

__global__ void prep_kernel(const float4* __restrict__ x4,
                            const float* __restrict__ w,
                            float* __restrict__ Af,
                            float* __restrict__ Bf,
                            ushort4* __restrict__ xh4) {
    int gid = blockIdx.x * blockDim.x + threadIdx.x;
    int node = gid >> 5;
    int t = threadIdx.x & 31;
    int h = t >> 3;
    int q8 = t & 7;

    float4 xv = x4[node * 32 + t];

    ushort4 u;
    u.x = __half_as_ushort(__float2half(xv.x));
    u.y = __half_as_ushort(__float2half(xv.y));
    u.z = __half_as_ushort(__float2half(xv.z));
    u.w = __half_as_ushort(__float2half(xv.w));
    xh4[node * 32 + t] = u;

    const float4* w4 = (const float4*)w;
    float4 wi = w4[q8];
    float4 wj = w4[8 + q8];
    float pa = xv.x * wi.x + xv.y * wi.y + xv.z * wi.z + xv.w * wi.w;
    float pb = xv.x * wj.x + xv.y * wj.y + xv.z * wj.z + xv.w * wj.w;
    #pragma unroll
    for (int m = 4; m >= 1; m >>= 1) {
        pa += __shfl_xor(pa, m);
        pb += __shfl_xor(pb, m);
    }
    if (q8 == 0) {
        Af[node * 4 + h] = pa;
        Bf[node * 4 + h] = pb;
    }
}

// ============================================================================
// v7 path: hist+rank, in-place scan, atomic-free record scatter
// ============================================================================

// hist + per-edge rank (the atomicAdd we were already paying now produces rank)
__global__ void hist_rank_kernel(const int* __restrict__ ei,
                                 int* __restrict__ cnt,
                                 ushort* __restrict__ rank,
                                 int n_edges) {
    int base = blockIdx.x * (blockDim.x * 4) + threadIdx.x;
    #pragma unroll
    for (int u = 0; u < 4; ++u) {
        int e = base + u * 256;
        if (e < n_edges) {
            int i = ei[e];
            int r = atomicAdd(&cnt[i], 1);
            rank[e] = (ushort)r;   // coalesced write; deg << 65536 for this input
        }
    }
}

// in-place multi-block exclusive scan over cnt[0..n-1] -> offsets
__global__ void scan1_kernel(int* __restrict__ arr, int* __restrict__ bsums, int n) {
    __shared__ int lds[256];
    int i = blockIdx.x * 256 + threadIdx.x;
    int v = (i < n) ? arr[i] : 0;
    lds[threadIdx.x] = v;
    __syncthreads();
    for (int d = 1; d < 256; d <<= 1) {
        int t = (threadIdx.x >= d) ? lds[threadIdx.x - d] : 0;
        __syncthreads();
        lds[threadIdx.x] += t;
        __syncthreads();
    }
    if (i < n) arr[i] = lds[threadIdx.x] - v;
    if (threadIdx.x == 255) bsums[blockIdx.x] = lds[255];
}

__global__ void scan2_kernel(int* __restrict__ bsums, int* __restrict__ total_out,
                             int nb) {
    __shared__ int lds[256];
    int v = (threadIdx.x < nb) ? bsums[threadIdx.x] : 0;
    lds[threadIdx.x] = v;
    __syncthreads();
    for (int d = 1; d < 256; d <<= 1) {
        int t = (threadIdx.x >= d) ? lds[threadIdx.x - d] : 0;
        __syncthreads();
        lds[threadIdx.x] += t;
        __syncthreads();
    }
    if (threadIdx.x < nb) bsums[threadIdx.x] = lds[threadIdx.x] - v;
    if (threadIdx.x == 255) *total_out = lds[255];
}

__global__ void scan3_kernel(int* __restrict__ arr, const int* __restrict__ bsums,
                             int n) {
    int i = blockIdx.x * 256 + threadIdx.x;
    if (i < n) arr[i] += bsums[blockIdx.x];
}

// atomic-free record scatter: 8 independent chains per thread
__global__ void scatter_norank_kernel(const int* __restrict__ ei,
                                      const int* __restrict__ ej,
                                      const float* __restrict__ weights,
                                      const float4* __restrict__ A4,
                                      const float4* __restrict__ B4,
                                      const int* __restrict__ offs,
                                      const ushort* __restrict__ rank,
                                      uint4* __restrict__ rec,
                                      int n_edges) {
    int base = blockIdx.x * (blockDim.x * 8) + threadIdx.x;
    #pragma unroll
    for (int u = 0; u < 8; ++u) {
        int e = base + u * 256;
        if (e >= n_edges) continue;
        int i = ei[e];
        int j = ej[e];
        float we = weights[e];
        int p = offs[i] + (int)rank[e];
        float4 ai = A4[i];
        float4 bj = B4[j];
        float b0 = we / (1.0f + __expf(-(ai.x + bj.x)));
        float b1 = we / (1.0f + __expf(-(ai.y + bj.y)));
        float b2 = we / (1.0f + __expf(-(ai.z + bj.z)));
        float b3 = we / (1.0f + __expf(-(ai.w + bj.w)));
        uint w01 = (uint)__half_as_ushort(__float2half(b0)) |
                   ((uint)__half_as_ushort(__float2half(b1)) << 16);
        uint w23 = (uint)__half_as_ushort(__float2half(b2)) |
                   ((uint)__half_as_ushort(__float2half(b3)) << 16);
        uint4 r;
        r.x = (uint)j; r.y = w01; r.z = w23; r.w = 0u;
        rec[p] = r;
    }
}

// gather: exp-free inner loop, 16B broadcast record + fp16 x gather
__global__ void gather_rec_kernel(const ushort4* __restrict__ xh4,
                                  const int* __restrict__ offs,
                                  const uint4* __restrict__ rec,
                                  float4* __restrict__ out4) {
    int gid = blockIdx.x * blockDim.x + threadIdx.x;
    int node = gid >> 5;
    int t = threadIdx.x & 31;
    int h = t >> 3;

    int start = offs[node];
    int end = offs[node + 1];
    float4 acc = make_float4(0.f, 0.f, 0.f, 0.f);
    #pragma unroll 4
    for (int k = start; k < end; ++k) {
        uint4 r = rec[k];
        int j = (int)r.x;
        uint wrd = (h < 2) ? r.y : r.z;
        ushort hw = (h & 1) ? (ushort)(wrd >> 16) : (ushort)(wrd & 0xffffu);
        float beta = __half2float(__ushort_as_half(hw));
        ushort4 xv = xh4[j * 32 + t];
        acc.x += __half2float(__ushort_as_half(xv.x)) * beta;
        acc.y += __half2float(__ushort_as_half(xv.y)) * beta;
        acc.z += __half2float(__ushort_as_half(xv.z)) * beta;
        acc.w += __half2float(__ushort_as_half(xv.w)) * beta;
    }
    vfloat4 av; av.x = acc.x; av.y = acc.y; av.z = acc.z; av.w = acc.w;
    __builtin_nontemporal_store(av, (vfloat4*)&out4[node * 32 + t]);
}

// ============================================================================
// v3 fallback (round-4 verified): atomic cursor scatter
// ============================================================================

__global__ void hist_kernel(const int* __restrict__ ei, int* __restrict__ cnt,
                            int n_edges) {
    int e = blockIdx.x * blockDim.x + threadIdx.x;
    if (e < n_edges) atomicAdd(&cnt[ei[e]], 1);
}

__global__ void scan1b_kernel(const int* __restrict__ cnt, int* __restrict__ offs,
                              int* __restrict__ bsums, int n) {
    __shared__ int lds[256];
    int i = blockIdx.x * 256 + threadIdx.x;
    int v = (i < n) ? cnt[i] : 0;
    lds[threadIdx.x] = v;
    __syncthreads();
    for (int d = 1; d < 256; d <<= 1) {
        int t = (threadIdx.x >= d) ? lds[threadIdx.x - d] : 0;
        __syncthreads();
        lds[threadIdx.x] += t;
        __syncthreads();
    }
    if (i < n) offs[i] = lds[threadIdx.x] - v;
    if (threadIdx.x == 255) bsums[blockIdx.x] = lds[255];
}

__global__ void scan3b_kernel(int* __restrict__ offs, int* __restrict__ cursor,
                              const int* __restrict__ bsums, int n) {
    int i = blockIdx.x * 256 + threadIdx.x;
    if (i < n) {
        int o = offs[i] + bsums[blockIdx.x];
        offs[i] = o;
        cursor[i] = o;
    }
}

__global__ void scatter_rec_kernel(const int* __restrict__ ei,
                                   const int* __restrict__ ej,
                                   const float* __restrict__ weights,
                                   const float4* __restrict__ A4,
                                   const float4* __restrict__ B4,
                                   int* __restrict__ cursor,
                                   uint4* __restrict__ rec,
                                   int n_edges) {
    int base = blockIdx.x * (blockDim.x * 4) + threadIdx.x;
    #pragma unroll
    for (int u = 0; u < 4; ++u) {
        int e = base + u * 256;
        if (e >= n_edges) continue;
        int i = ei[e];
        int j = ej[e];
        float we = weights[e];
        float4 ai = A4[i];
        float4 bj = B4[j];
        float b0 = we / (1.0f + __expf(-(ai.x + bj.x)));
        float b1 = we / (1.0f + __expf(-(ai.y + bj.y)));
        float b2 = we / (1.0f + __expf(-(ai.z + bj.z)));
        float b3 = we / (1.0f + __expf(-(ai.w + bj.w)));
        uint w01 = (uint)__half_as_ushort(__float2half(b0)) |
                   ((uint)__half_as_ushort(__float2half(b1)) << 16);
        uint w23 = (uint)__half_as_ushort(__float2half(b2)) |
                   ((uint)__half_as_ushort(__float2half(b3)) << 16);
        int p = atomicAdd(&cursor[i], 1);
        uint4 r;
        r.x = (uint)j; r.y = w01; r.z = w23; r.w = 0u;
        rec[p] = r;
    }
}

// ============================================================================
// v0 ultimate fallback: atomic scatter
// ============================================================================

__global__ void node_dots_kernel(const float* __restrict__ x,
                                 const float* __restrict__ w,
                                 float* __restrict__ ab,
                                 int n_nodes) {
    int gid = blockIdx.x * blockDim.x + threadIdx.x;
    int node = gid >> 7;
    int t = threadIdx.x & 127;
    if (node >= n_nodes) return;
    int h = t >> 5;
    int c = t & 31;
    float xv = x[node * FDIM + t];
    float pa = xv * w[c];
    float pb = xv * w[OUT_CH + c];
    #pragma unroll
    for (int m = 16; m >= 1; m >>= 1) {
        pa += __shfl_xor(pa, m);
        pb += __shfl_xor(pb, m);
    }
    if (c == 0) {
        ab[node * 8 + h * 2 + 0] = pa;
        ab[node * 8 + h * 2 + 1] = pb;
    }
}

__global__ void edge_scatter_kernel(const float* __restrict__ x,
                                    const int* __restrict__ ei_arr,
                                    const int* __restrict__ ej_arr,
                                    const float* __restrict__ weights,
                                    const float* __restrict__ ab,
                                    float* __restrict__ out,
                                    int n_edges) {
    int gid = blockIdx.x * blockDim.x + threadIdx.x;
    int e = gid >> 7;
    int t = threadIdx.x & 127;
    if (e >= n_edges) return;
    int h = t >> 5;
    int i = ei_arr[e];
    int j = ej_arr[e];
    float alpha = ab[i * 8 + h * 2 + 0] + ab[j * 8 + h * 2 + 1];
    float beta = weights[e] / (1.0f + __expf(-alpha));
    atomicAdd(&out[i * FDIM + t], x[j * FDIM + t] * beta);
}

// ============================================================================

extern "C" void kernel_launch(void* const* d_in, const int* in_sizes, int n_in,
                              void* d_out, int out_size, void* d_ws, size_t ws_size,
                              hipStream_t stream) {
    const float* x       = (const float*)d_in[0];
    const int*   eidx    = (const int*)d_in[1];
    const float* weights = (const float*)d_in[2];
    const float* w       = (const float*)d_in[3];
    float* out = (float*)d_out;

    const int* ei_arr = eidx;
    const int* ej_arr = eidx + N_EDGES;

    const int NB = (N_NODES + 255) / 256;  // scan blocks (196)

    // ---- v7 workspace layout ----
    // xh: 12.8MB | A: .8MB | B: .8MB | rec: 12.8MB | rank: 1.6MB |
    // offs(cnt in-place): (N+1)*4 | bsums: 1KB  => ~29.1MB
    {
        char* p = (char*)d_ws;
        ushort4* xh4  = (ushort4*)p;   p += (size_t)N_NODES * FDIM * 2;
        float*   Af   = (float*)p;     p += (size_t)N_NODES * 4 * 4;
        float*   Bf   = (float*)p;     p += (size_t)N_NODES * 4 * 4;
        uint4*   rec  = (uint4*)p;     p += (size_t)N_EDGES * 16;
        ushort*  rank = (ushort*)p;    p += (size_t)N_EDGES * 2;
        int*     offs = (int*)p;       p += (size_t)(N_NODES + 1) * 4;
        int*     bsums= (int*)p;       p += (size_t)256 * 4;
        size_t need_v7 = (size_t)(p - (char*)d_ws);

        if (ws_size >= need_v7) {
            hipMemsetAsync(offs, 0, (size_t)(N_NODES + 1) * sizeof(int), stream);
            prep_kernel<<<(N_NODES * 32) / 256, 256, 0, stream>>>(
                (const float4*)x, w, Af, Bf, xh4);
            hist_rank_kernel<<<(N_EDGES + 1023) / 1024, 256, 0, stream>>>(
                ei_arr, offs, rank, N_EDGES);
            scan1_kernel<<<NB, 256, 0, stream>>>(offs, bsums, N_NODES);
            scan2_kernel<<<1, 256, 0, stream>>>(bsums, offs + N_NODES, NB);
            scan3_kernel<<<NB, 256, 0, stream>>>(offs, bsums, N_NODES);
            scatter_norank_kernel<<<(N_EDGES + 2047) / 2048, 256, 0, stream>>>(
                ei_arr, ej_arr, weights, (const float4*)Af, (const float4*)Bf,
                offs, rank, rec, N_EDGES);
            gather_rec_kernel<<<(N_NODES * 32) / 256, 256, 0, stream>>>(
                xh4, offs, rec, (float4*)out);
            return;
        }
    }

    // ---- v3 fallback (round-4 verified) ----
    {
        char* p = (char*)d_ws;
        uint4*   rec  = (uint4*)p;                 p += (size_t)N_EDGES * 16;
        ushort4* xh4  = (ushort4*)p;               p += (size_t)N_NODES * FDIM * 2;
        float*   Af   = (float*)p;                 p += (size_t)N_NODES * 4 * 4;
        float*   Bf   = (float*)p;                 p += (size_t)N_NODES * 4 * 4;
        int*     cnt  = (int*)p;                   p += (size_t)N_NODES * 4;
        int*     offs = (int*)p;                   p += (size_t)(N_NODES + 1) * 4;
        int*     cur  = (int*)p;                   p += (size_t)N_NODES * 4;
        int*     bsums= (int*)p;                   p += (size_t)256 * 4;
        size_t need_v3 = (size_t)(p - (char*)d_ws);

        if (ws_size >= need_v3) {
            hipMemsetAsync(cnt, 0, (size_t)N_NODES * sizeof(int), stream);
            prep_kernel<<<(N_NODES * 32) / 256, 256, 0, stream>>>(
                (const float4*)x, w, Af, Bf, xh4);
            hist_kernel<<<(N_EDGES + 255) / 256, 256, 0, stream>>>(
                ei_arr, cnt, N_EDGES);
            scan1b_kernel<<<NB, 256, 0, stream>>>(cnt, offs, bsums, N_NODES);
            scan2_kernel<<<1, 256, 0, stream>>>(bsums, offs + N_NODES, NB);
            scan3b_kernel<<<NB, 256, 0, stream>>>(offs, cur, bsums, N_NODES);
            scatter_rec_kernel<<<(N_EDGES + 1023) / 1024, 256, 0, stream>>>(
                ei_arr, ej_arr, weights, (const float4*)Af, (const float4*)Bf,
                cur, rec, N_EDGES);
            gather_rec_kernel<<<(N_NODES * 32) / 256, 256, 0, stream>>>(
                xh4, offs, rec, (float4*)out);
            return;
        }
    }

    // ---- v0 atomic fallback ----
    {
        float* ab = (float*)d_ws;  // 1.6MB
        int grid = (N_NODES * FDIM + 255) / 256;
        node_dots_kernel<<<grid, 256, 0, stream>>>(x, w, ab, N_NODES);
        hipMemsetAsync(d_out, 0, (size_t)out_size * sizeof(float), stream);
        long long threads_total = (long long)N_EDGES * FDIM;
        long long g = (threads_total + 255) / 256;
        edge_scatter_kernel<<<(int)g, 256, 0, stream>>>(
            x, ei_arr, ej_arr, weights, ab, out, N_EDGES);
    }
}

// Round 8
// 119.073 us; speedup vs baseline: 1.4676x; 1.0184x over previous
//
#include <hip/hip_runtime.h>
#include <hip/hip_bf16.h>
#include <hip/hip_fp16.h>

#define N_NODES 50000
#define N_EDGES 800000
#define HEADS 4
#define OUT_CH 32
#define FDIM (HEADS * OUT_CH)   // 128

typedef float vfloat4 __attribute__((ext_vector_type(4)));

#define PREP_BLOCKS ((N_NODES * 32) / 256)            // 6250
#define HIST_BLOCKS ((N_EDGES + 511) / 512)           // 1563 (2 edges/thread)

// ============================================================================
// v8: fused prep + hist_rank (independent work packed into one launch)
// ============================================================================

__global__ void prep_hist_kernel(const float4* __restrict__ x4,
                                 const float* __restrict__ w,
                                 float* __restrict__ Af,
                                 float* __restrict__ Bf,
                                 ushort4* __restrict__ xh4,
                                 const int* __restrict__ ei,
                                 int* __restrict__ cnt,
                                 ushort* __restrict__ rank) {
    int b = blockIdx.x;
    if (b < PREP_BLOCKS) {
        // ---- prep: A/B dots + fp16 x-table ----
        int gid = b * 256 + threadIdx.x;
        int node = gid >> 5;
        int t = threadIdx.x & 31;
        int h = t >> 3;
        int q8 = t & 7;

        float4 xv = x4[node * 32 + t];

        ushort4 u;
        u.x = __half_as_ushort(__float2half(xv.x));
        u.y = __half_as_ushort(__float2half(xv.y));
        u.z = __half_as_ushort(__float2half(xv.z));
        u.w = __half_as_ushort(__float2half(xv.w));
        xh4[node * 32 + t] = u;

        const float4* w4 = (const float4*)w;
        float4 wi = w4[q8];
        float4 wj = w4[8 + q8];
        float pa = xv.x * wi.x + xv.y * wi.y + xv.z * wi.z + xv.w * wi.w;
        float pb = xv.x * wj.x + xv.y * wj.y + xv.z * wj.z + xv.w * wj.w;
        #pragma unroll
        for (int m = 4; m >= 1; m >>= 1) {
            pa += __shfl_xor(pa, m);
            pb += __shfl_xor(pb, m);
        }
        if (q8 == 0) {
            Af[node * 4 + h] = pa;
            Bf[node * 4 + h] = pb;
        }
    } else {
        // ---- hist + rank: 2 edges/thread ----
        int hb = b - PREP_BLOCKS;
        int base = hb * 512 + threadIdx.x;
        #pragma unroll
        for (int u = 0; u < 2; ++u) {
            int e = base + u * 256;
            if (e < N_EDGES) {
                int i = ei[e];
                int r = atomicAdd(&cnt[i], 1);
                rank[e] = (ushort)r;
            }
        }
    }
}

// ============================================================================
// scan (in-place over cnt -> offsets)
// ============================================================================

__global__ void scan1_kernel(int* __restrict__ arr, int* __restrict__ bsums, int n) {
    __shared__ int lds[256];
    int i = blockIdx.x * 256 + threadIdx.x;
    int v = (i < n) ? arr[i] : 0;
    lds[threadIdx.x] = v;
    __syncthreads();
    for (int d = 1; d < 256; d <<= 1) {
        int t = (threadIdx.x >= d) ? lds[threadIdx.x - d] : 0;
        __syncthreads();
        lds[threadIdx.x] += t;
        __syncthreads();
    }
    if (i < n) arr[i] = lds[threadIdx.x] - v;
    if (threadIdx.x == 255) bsums[blockIdx.x] = lds[255];
}

__global__ void scan2_kernel(int* __restrict__ bsums, int* __restrict__ total_out,
                             int nb) {
    __shared__ int lds[256];
    int v = (threadIdx.x < nb) ? bsums[threadIdx.x] : 0;
    lds[threadIdx.x] = v;
    __syncthreads();
    for (int d = 1; d < 256; d <<= 1) {
        int t = (threadIdx.x >= d) ? lds[threadIdx.x - d] : 0;
        __syncthreads();
        lds[threadIdx.x] += t;
        __syncthreads();
    }
    if (threadIdx.x < nb) bsums[threadIdx.x] = lds[threadIdx.x] - v;
    if (threadIdx.x == 255) *total_out = lds[255];
}

__global__ void scan3_kernel(int* __restrict__ arr, const int* __restrict__ bsums,
                             int n) {
    int i = blockIdx.x * 256 + threadIdx.x;
    if (i < n) arr[i] += bsums[blockIdx.x];
}

// ============================================================================
// atomic-free record scatter: 2 edges/thread, high occupancy
// ============================================================================

__global__ void scatter_norank_kernel(const int* __restrict__ ei,
                                      const int* __restrict__ ej,
                                      const float* __restrict__ weights,
                                      const float4* __restrict__ A4,
                                      const float4* __restrict__ B4,
                                      const int* __restrict__ offs,
                                      const ushort* __restrict__ rank,
                                      uint4* __restrict__ rec,
                                      int n_edges) {
    int base = blockIdx.x * (blockDim.x * 2) + threadIdx.x;
    #pragma unroll
    for (int u = 0; u < 2; ++u) {
        int e = base + u * 256;
        if (e >= n_edges) continue;
        int i = ei[e];
        int j = ej[e];
        float we = weights[e];
        int p = offs[i] + (int)rank[e];
        float4 ai = A4[i];
        float4 bj = B4[j];
        float b0 = we / (1.0f + __expf(-(ai.x + bj.x)));
        float b1 = we / (1.0f + __expf(-(ai.y + bj.y)));
        float b2 = we / (1.0f + __expf(-(ai.z + bj.z)));
        float b3 = we / (1.0f + __expf(-(ai.w + bj.w)));
        uint w01 = (uint)__half_as_ushort(__float2half(b0)) |
                   ((uint)__half_as_ushort(__float2half(b1)) << 16);
        uint w23 = (uint)__half_as_ushort(__float2half(b2)) |
                   ((uint)__half_as_ushort(__float2half(b3)) << 16);
        uint4 r;
        r.x = (uint)j; r.y = w01; r.z = w23; r.w = 0u;
        rec[p] = r;
    }
}

// ============================================================================
// gather: exp-free inner loop, 16B broadcast record + fp16 x gather
// ============================================================================

__global__ void gather_rec_kernel(const ushort4* __restrict__ xh4,
                                  const int* __restrict__ offs,
                                  const uint4* __restrict__ rec,
                                  float4* __restrict__ out4) {
    int gid = blockIdx.x * blockDim.x + threadIdx.x;
    int node = gid >> 5;
    int t = threadIdx.x & 31;
    int h = t >> 3;

    int start = offs[node];
    int end = offs[node + 1];
    float4 acc = make_float4(0.f, 0.f, 0.f, 0.f);
    #pragma unroll 4
    for (int k = start; k < end; ++k) {
        uint4 r = rec[k];
        int j = (int)r.x;
        uint wrd = (h < 2) ? r.y : r.z;
        ushort hw = (h & 1) ? (ushort)(wrd >> 16) : (ushort)(wrd & 0xffffu);
        float beta = __half2float(__ushort_as_half(hw));
        ushort4 xv = xh4[j * 32 + t];
        acc.x += __half2float(__ushort_as_half(xv.x)) * beta;
        acc.y += __half2float(__ushort_as_half(xv.y)) * beta;
        acc.z += __half2float(__ushort_as_half(xv.z)) * beta;
        acc.w += __half2float(__ushort_as_half(xv.w)) * beta;
    }
    vfloat4 av; av.x = acc.x; av.y = acc.y; av.z = acc.z; av.w = acc.w;
    __builtin_nontemporal_store(av, (vfloat4*)&out4[node * 32 + t]);
}

// ============================================================================
// v0 ultimate fallback: atomic scatter
// ============================================================================

__global__ void node_dots_kernel(const float* __restrict__ x,
                                 const float* __restrict__ w,
                                 float* __restrict__ ab,
                                 int n_nodes) {
    int gid = blockIdx.x * blockDim.x + threadIdx.x;
    int node = gid >> 7;
    int t = threadIdx.x & 127;
    if (node >= n_nodes) return;
    int h = t >> 5;
    int c = t & 31;
    float xv = x[node * FDIM + t];
    float pa = xv * w[c];
    float pb = xv * w[OUT_CH + c];
    #pragma unroll
    for (int m = 16; m >= 1; m >>= 1) {
        pa += __shfl_xor(pa, m);
        pb += __shfl_xor(pb, m);
    }
    if (c == 0) {
        ab[node * 8 + h * 2 + 0] = pa;
        ab[node * 8 + h * 2 + 1] = pb;
    }
}

__global__ void edge_scatter_kernel(const float* __restrict__ x,
                                    const int* __restrict__ ei_arr,
                                    const int* __restrict__ ej_arr,
                                    const float* __restrict__ weights,
                                    const float* __restrict__ ab,
                                    float* __restrict__ out,
                                    int n_edges) {
    int gid = blockIdx.x * blockDim.x + threadIdx.x;
    int e = gid >> 7;
    int t = threadIdx.x & 127;
    if (e >= n_edges) return;
    int h = t >> 5;
    int i = ei_arr[e];
    int j = ej_arr[e];
    float alpha = ab[i * 8 + h * 2 + 0] + ab[j * 8 + h * 2 + 1];
    float beta = weights[e] / (1.0f + __expf(-alpha));
    atomicAdd(&out[i * FDIM + t], x[j * FDIM + t] * beta);
}

// ============================================================================

extern "C" void kernel_launch(void* const* d_in, const int* in_sizes, int n_in,
                              void* d_out, int out_size, void* d_ws, size_t ws_size,
                              hipStream_t stream) {
    const float* x       = (const float*)d_in[0];
    const int*   eidx    = (const int*)d_in[1];
    const float* weights = (const float*)d_in[2];
    const float* w       = (const float*)d_in[3];
    float* out = (float*)d_out;

    const int* ei_arr = eidx;
    const int* ej_arr = eidx + N_EDGES;

    const int NB = (N_NODES + 255) / 256;  // scan blocks (196)

    // ---- v8 workspace layout ----
    // xh: 12.8MB | A: .8MB | B: .8MB | rec: 12.8MB | rank: 1.6MB |
    // offs(cnt in-place): (N+1)*4 | bsums: 1KB  => ~29.1MB
    {
        char* p = (char*)d_ws;
        ushort4* xh4  = (ushort4*)p;   p += (size_t)N_NODES * FDIM * 2;
        float*   Af   = (float*)p;     p += (size_t)N_NODES * 4 * 4;
        float*   Bf   = (float*)p;     p += (size_t)N_NODES * 4 * 4;
        uint4*   rec  = (uint4*)p;     p += (size_t)N_EDGES * 16;
        ushort*  rank = (ushort*)p;    p += (size_t)N_EDGES * 2;
        int*     offs = (int*)p;       p += (size_t)(N_NODES + 1) * 4;
        int*     bsums= (int*)p;       p += (size_t)256 * 4;
        size_t need_v8 = (size_t)(p - (char*)d_ws);

        if (ws_size >= need_v8) {
            hipMemsetAsync(offs, 0, (size_t)(N_NODES + 1) * sizeof(int), stream);
            prep_hist_kernel<<<PREP_BLOCKS + HIST_BLOCKS, 256, 0, stream>>>(
                (const float4*)x, w, Af, Bf, xh4, ei_arr, offs, rank);
            scan1_kernel<<<NB, 256, 0, stream>>>(offs, bsums, N_NODES);
            scan2_kernel<<<1, 256, 0, stream>>>(bsums, offs + N_NODES, NB);
            scan3_kernel<<<NB, 256, 0, stream>>>(offs, bsums, N_NODES);
            scatter_norank_kernel<<<(N_EDGES + 511) / 512, 256, 0, stream>>>(
                ei_arr, ej_arr, weights, (const float4*)Af, (const float4*)Bf,
                offs, rank, rec, N_EDGES);
            gather_rec_kernel<<<(N_NODES * 32) / 256, 256, 0, stream>>>(
                xh4, offs, rec, (float4*)out);
            return;
        }
    }

    // ---- v0 atomic fallback ----
    {
        float* ab = (float*)d_ws;  // 1.6MB
        int grid = (N_NODES * FDIM + 255) / 256;
        node_dots_kernel<<<grid, 256, 0, stream>>>(x, w, ab, N_NODES);
        hipMemsetAsync(d_out, 0, (size_t)out_size * sizeof(float), stream);
        long long threads_total = (long long)N_EDGES * FDIM;
        long long g = (threads_total + 255) / 256;
        edge_scatter_kernel<<<(int)g, 256, 0, stream>>>(
            x, ei_arr, ej_arr, weights, ab, out, N_EDGES);
    }
}

// Round 9
// 116.761 us; speedup vs baseline: 1.4967x; 1.0198x over previous
//
#include <hip/hip_runtime.h>
#include <hip/hip_bf16.h>
#include <hip/hip_fp16.h>

#define N_NODES 50000
#define N_EDGES 800000
#define HEADS 4
#define OUT_CH 32
#define FDIM (HEADS * OUT_CH)   // 128

typedef float vfloat4 __attribute__((ext_vector_type(4)));

// ============================================================================
// prep: A/B node dots + fp16 x-table
// ============================================================================

__global__ void prep_kernel(const float4* __restrict__ x4,
                            const float* __restrict__ w,
                            float* __restrict__ Af,
                            float* __restrict__ Bf,
                            ushort4* __restrict__ xh4) {
    int gid = blockIdx.x * blockDim.x + threadIdx.x;
    int node = gid >> 5;
    int t = threadIdx.x & 31;
    int h = t >> 3;
    int q8 = t & 7;

    float4 xv = x4[node * 32 + t];

    ushort4 u;
    u.x = __half_as_ushort(__float2half(xv.x));
    u.y = __half_as_ushort(__float2half(xv.y));
    u.z = __half_as_ushort(__float2half(xv.z));
    u.w = __half_as_ushort(__float2half(xv.w));
    xh4[node * 32 + t] = u;

    const float4* w4 = (const float4*)w;
    float4 wi = w4[q8];
    float4 wj = w4[8 + q8];
    float pa = xv.x * wi.x + xv.y * wi.y + xv.z * wi.z + xv.w * wi.w;
    float pb = xv.x * wj.x + xv.y * wj.y + xv.z * wj.z + xv.w * wj.w;
    #pragma unroll
    for (int m = 4; m >= 1; m >>= 1) {
        pa += __shfl_xor(pa, m);
        pb += __shfl_xor(pb, m);
    }
    if (q8 == 0) {
        Af[node * 4 + h] = pa;
        Bf[node * 4 + h] = pb;
    }
}

// ============================================================================
// hist + rank: counters padded to one per 64B line (shift=4) to kill
// cross-XCD line ping-pong; shift=0 degenerates to packed counters.
// ============================================================================

__global__ void hist_rank_kernel(const int* __restrict__ ei,
                                 int* __restrict__ cnt,
                                 ushort* __restrict__ rank,
                                 int n_edges, int shift) {
    int base = blockIdx.x * 512 + threadIdx.x;
    #pragma unroll
    for (int u = 0; u < 2; ++u) {
        int e = base + u * 256;
        if (e < n_edges) {
            int i = ei[e];
            int r = atomicAdd(&cnt[i << shift], 1);
            rank[e] = (ushort)r;
        }
    }
}

// ============================================================================
// scan: compact strided counters -> offs (exclusive), multi-block
// ============================================================================

__global__ void scan1_kernel(const int* __restrict__ cnt, int* __restrict__ offs,
                             int* __restrict__ bsums, int n, int shift) {
    __shared__ int lds[256];
    int i = blockIdx.x * 256 + threadIdx.x;
    int v = (i < n) ? cnt[i << shift] : 0;
    lds[threadIdx.x] = v;
    __syncthreads();
    for (int d = 1; d < 256; d <<= 1) {
        int t = (threadIdx.x >= d) ? lds[threadIdx.x - d] : 0;
        __syncthreads();
        lds[threadIdx.x] += t;
        __syncthreads();
    }
    if (i < n) offs[i] = lds[threadIdx.x] - v;
    if (threadIdx.x == 255) bsums[blockIdx.x] = lds[255];
}

__global__ void scan2_kernel(int* __restrict__ bsums, int* __restrict__ total_out,
                             int nb) {
    __shared__ int lds[256];
    int v = (threadIdx.x < nb) ? bsums[threadIdx.x] : 0;
    lds[threadIdx.x] = v;
    __syncthreads();
    for (int d = 1; d < 256; d <<= 1) {
        int t = (threadIdx.x >= d) ? lds[threadIdx.x - d] : 0;
        __syncthreads();
        lds[threadIdx.x] += t;
        __syncthreads();
    }
    if (threadIdx.x < nb) bsums[threadIdx.x] = lds[threadIdx.x] - v;
    if (threadIdx.x == 255) *total_out = lds[255];
}

__global__ void scan3_kernel(int* __restrict__ arr, const int* __restrict__ bsums,
                             int n) {
    int i = blockIdx.x * 256 + threadIdx.x;
    if (i < n) arr[i] += bsums[blockIdx.x];
}

// ============================================================================
// atomic-free record scatter: 2 edges/thread, high occupancy
// ============================================================================

__global__ void scatter_norank_kernel(const int* __restrict__ ei,
                                      const int* __restrict__ ej,
                                      const float* __restrict__ weights,
                                      const float4* __restrict__ A4,
                                      const float4* __restrict__ B4,
                                      const int* __restrict__ offs,
                                      const ushort* __restrict__ rank,
                                      uint4* __restrict__ rec,
                                      int n_edges) {
    int base = blockIdx.x * (blockDim.x * 2) + threadIdx.x;
    #pragma unroll
    for (int u = 0; u < 2; ++u) {
        int e = base + u * 256;
        if (e >= n_edges) continue;
        int i = ei[e];
        int j = ej[e];
        float we = weights[e];
        int p = offs[i] + (int)rank[e];
        float4 ai = A4[i];
        float4 bj = B4[j];
        float b0 = we / (1.0f + __expf(-(ai.x + bj.x)));
        float b1 = we / (1.0f + __expf(-(ai.y + bj.y)));
        float b2 = we / (1.0f + __expf(-(ai.z + bj.z)));
        float b3 = we / (1.0f + __expf(-(ai.w + bj.w)));
        uint w01 = (uint)__half_as_ushort(__float2half(b0)) |
                   ((uint)__half_as_ushort(__float2half(b1)) << 16);
        uint w23 = (uint)__half_as_ushort(__float2half(b2)) |
                   ((uint)__half_as_ushort(__float2half(b3)) << 16);
        uint4 r;
        r.x = (uint)j; r.y = w01; r.z = w23; r.w = 0u;
        rec[p] = r;
    }
}

// ============================================================================
// gather: exp-free inner loop, 16B broadcast record + fp16 x gather
// ============================================================================

__global__ void gather_rec_kernel(const ushort4* __restrict__ xh4,
                                  const int* __restrict__ offs,
                                  const uint4* __restrict__ rec,
                                  float4* __restrict__ out4) {
    int gid = blockIdx.x * blockDim.x + threadIdx.x;
    int node = gid >> 5;
    int t = threadIdx.x & 31;
    int h = t >> 3;

    int start = offs[node];
    int end = offs[node + 1];
    float4 acc = make_float4(0.f, 0.f, 0.f, 0.f);
    #pragma unroll 4
    for (int k = start; k < end; ++k) {
        uint4 r = rec[k];
        int j = (int)r.x;
        uint wrd = (h < 2) ? r.y : r.z;
        ushort hw = (h & 1) ? (ushort)(wrd >> 16) : (ushort)(wrd & 0xffffu);
        float beta = __half2float(__ushort_as_half(hw));
        ushort4 xv = xh4[j * 32 + t];
        acc.x += __half2float(__ushort_as_half(xv.x)) * beta;
        acc.y += __half2float(__ushort_as_half(xv.y)) * beta;
        acc.z += __half2float(__ushort_as_half(xv.z)) * beta;
        acc.w += __half2float(__ushort_as_half(xv.w)) * beta;
    }
    vfloat4 av; av.x = acc.x; av.y = acc.y; av.z = acc.z; av.w = acc.w;
    __builtin_nontemporal_store(av, (vfloat4*)&out4[node * 32 + t]);
}

// ============================================================================
// v0 ultimate fallback: atomic scatter
// ============================================================================

__global__ void node_dots_kernel(const float* __restrict__ x,
                                 const float* __restrict__ w,
                                 float* __restrict__ ab,
                                 int n_nodes) {
    int gid = blockIdx.x * blockDim.x + threadIdx.x;
    int node = gid >> 7;
    int t = threadIdx.x & 127;
    if (node >= n_nodes) return;
    int h = t >> 5;
    int c = t & 31;
    float xv = x[node * FDIM + t];
    float pa = xv * w[c];
    float pb = xv * w[OUT_CH + c];
    #pragma unroll
    for (int m = 16; m >= 1; m >>= 1) {
        pa += __shfl_xor(pa, m);
        pb += __shfl_xor(pb, m);
    }
    if (c == 0) {
        ab[node * 8 + h * 2 + 0] = pa;
        ab[node * 8 + h * 2 + 1] = pb;
    }
}

__global__ void edge_scatter_kernel(const float* __restrict__ x,
                                    const int* __restrict__ ei_arr,
                                    const int* __restrict__ ej_arr,
                                    const float* __restrict__ weights,
                                    const float* __restrict__ ab,
                                    float* __restrict__ out,
                                    int n_edges) {
    int gid = blockIdx.x * blockDim.x + threadIdx.x;
    int e = gid >> 7;
    int t = threadIdx.x & 127;
    if (e >= n_edges) return;
    int h = t >> 5;
    int i = ei_arr[e];
    int j = ej_arr[e];
    float alpha = ab[i * 8 + h * 2 + 0] + ab[j * 8 + h * 2 + 1];
    float beta = weights[e] / (1.0f + __expf(-alpha));
    atomicAdd(&out[i * FDIM + t], x[j * FDIM + t] * beta);
}

// ============================================================================

extern "C" void kernel_launch(void* const* d_in, const int* in_sizes, int n_in,
                              void* d_out, int out_size, void* d_ws, size_t ws_size,
                              hipStream_t stream) {
    const float* x       = (const float*)d_in[0];
    const int*   eidx    = (const int*)d_in[1];
    const float* weights = (const float*)d_in[2];
    const float* w       = (const float*)d_in[3];
    float* out = (float*)d_out;

    const int* ei_arr = eidx;
    const int* ej_arr = eidx + N_EDGES;

    const int NB = (N_NODES + 255) / 256;  // scan blocks (196)

    // ---- v9 workspace layout ----
    // xh: 12.8MB | A: .8MB | B: .8MB | rec: 12.8MB | rank: 1.6MB |
    // offs: (N+1)*4 | bsums: 1KB | cnt_pad: N*stride*4
    // stride=16 (64B padded) if ws allows (~32.4MB), else stride=1 (~29.3MB)
    {
        char* p = (char*)d_ws;
        ushort4* xh4  = (ushort4*)p;   p += (size_t)N_NODES * FDIM * 2;
        float*   Af   = (float*)p;     p += (size_t)N_NODES * 4 * 4;
        float*   Bf   = (float*)p;     p += (size_t)N_NODES * 4 * 4;
        uint4*   rec  = (uint4*)p;     p += (size_t)N_EDGES * 16;
        ushort*  rank = (ushort*)p;    p += (size_t)N_EDGES * 2;
        int*     offs = (int*)p;       p += (size_t)(N_NODES + 1) * 4;
        int*     bsums= (int*)p;       p += (size_t)256 * 4;
        int*     cnt  = (int*)p;       // strided counters live at the end
        size_t base_need = (size_t)(p - (char*)d_ws);
        size_t need_pad  = base_need + (size_t)N_NODES * 16 * 4;  // shift=4
        size_t need_min  = base_need + (size_t)N_NODES * 4;       // shift=0

        int shift = -1;
        if (ws_size >= need_pad)      shift = 4;
        else if (ws_size >= need_min) shift = 0;

        if (shift >= 0) {
            size_t cnt_bytes = (size_t)N_NODES * (4 << shift);
            hipMemsetAsync(cnt, 0, cnt_bytes, stream);
            prep_kernel<<<(N_NODES * 32) / 256, 256, 0, stream>>>(
                (const float4*)x, w, Af, Bf, xh4);
            hist_rank_kernel<<<(N_EDGES + 511) / 512, 256, 0, stream>>>(
                ei_arr, cnt, rank, N_EDGES, shift);
            scan1_kernel<<<NB, 256, 0, stream>>>(cnt, offs, bsums, N_NODES, shift);
            scan2_kernel<<<1, 256, 0, stream>>>(bsums, offs + N_NODES, NB);
            scan3_kernel<<<NB, 256, 0, stream>>>(offs, bsums, N_NODES);
            scatter_norank_kernel<<<(N_EDGES + 511) / 512, 256, 0, stream>>>(
                ei_arr, ej_arr, weights, (const float4*)Af, (const float4*)Bf,
                offs, rank, rec, N_EDGES);
            gather_rec_kernel<<<(N_NODES * 32) / 256, 256, 0, stream>>>(
                xh4, offs, rec, (float4*)out);
            return;
        }
    }

    // ---- v0 atomic fallback ----
    {
        float* ab = (float*)d_ws;  // 1.6MB
        int grid = (N_NODES * FDIM + 255) / 256;
        node_dots_kernel<<<grid, 256, 0, stream>>>(x, w, ab, N_NODES);
        hipMemsetAsync(d_out, 0, (size_t)out_size * sizeof(float), stream);
        long long threads_total = (long long)N_EDGES * FDIM;
        long long g = (threads_total + 255) / 256;
        edge_scatter_kernel<<<(int)g, 256, 0, stream>>>(
            x, ei_arr, ej_arr, weights, ab, out, N_EDGES);
    }
}

// Round 10
// 107.661 us; speedup vs baseline: 1.6232x; 1.0845x over previous
//
#include <hip/hip_runtime.h>
#include <hip/hip_bf16.h>
#include <hip/hip_fp16.h>

#define N_NODES 50000
#define N_EDGES 800000
#define HEADS 4
#define OUT_CH 32
#define FDIM (HEADS * OUT_CH)   // 128

typedef float vfloat4 __attribute__((ext_vector_type(4)));

// ============================================================================
// prep: A/B node dots + fp16 x-table + zero the strided counters
// (cnt zeroing folded here to avoid rocclr's 41us latency-bound fill kernel)
// ============================================================================

__global__ void prep_kernel(const float4* __restrict__ x4,
                            const float* __restrict__ w,
                            float* __restrict__ Af,
                            float* __restrict__ Bf,
                            ushort4* __restrict__ xh4,
                            int4* __restrict__ cnt_zero,
                            int n_cnt4) {
    int gid = blockIdx.x * blockDim.x + threadIdx.x;

    // zero counters (first n_cnt4 threads, one int4 each — coalesced)
    if (gid < n_cnt4) cnt_zero[gid] = make_int4(0, 0, 0, 0);

    int node = gid >> 5;
    int t = threadIdx.x & 31;
    int h = t >> 3;
    int q8 = t & 7;

    float4 xv = x4[node * 32 + t];

    ushort4 u;
    u.x = __half_as_ushort(__float2half(xv.x));
    u.y = __half_as_ushort(__float2half(xv.y));
    u.z = __half_as_ushort(__float2half(xv.z));
    u.w = __half_as_ushort(__float2half(xv.w));
    xh4[node * 32 + t] = u;

    const float4* w4 = (const float4*)w;
    float4 wi = w4[q8];
    float4 wj = w4[8 + q8];
    float pa = xv.x * wi.x + xv.y * wi.y + xv.z * wi.z + xv.w * wi.w;
    float pb = xv.x * wj.x + xv.y * wj.y + xv.z * wj.z + xv.w * wj.w;
    #pragma unroll
    for (int m = 4; m >= 1; m >>= 1) {
        pa += __shfl_xor(pa, m);
        pb += __shfl_xor(pb, m);
    }
    if (q8 == 0) {
        Af[node * 4 + h] = pa;
        Bf[node * 4 + h] = pb;
    }
}

// ============================================================================
// hist + rank: counters padded to one per 64B line (shift=4) to kill
// cross-XCD line ping-pong; shift=0 degenerates to packed counters.
// ============================================================================

__global__ void hist_rank_kernel(const int* __restrict__ ei,
                                 int* __restrict__ cnt,
                                 ushort* __restrict__ rank,
                                 int n_edges, int shift) {
    int base = blockIdx.x * 512 + threadIdx.x;
    #pragma unroll
    for (int u = 0; u < 2; ++u) {
        int e = base + u * 256;
        if (e < n_edges) {
            int i = ei[e];
            int r = atomicAdd(&cnt[i << shift], 1);
            rank[e] = (ushort)r;
        }
    }
}

// ============================================================================
// scan: compact strided counters -> offs (exclusive), multi-block
// ============================================================================

__global__ void scan1_kernel(const int* __restrict__ cnt, int* __restrict__ offs,
                             int* __restrict__ bsums, int n, int shift) {
    __shared__ int lds[256];
    int i = blockIdx.x * 256 + threadIdx.x;
    int v = (i < n) ? cnt[i << shift] : 0;
    lds[threadIdx.x] = v;
    __syncthreads();
    for (int d = 1; d < 256; d <<= 1) {
        int t = (threadIdx.x >= d) ? lds[threadIdx.x - d] : 0;
        __syncthreads();
        lds[threadIdx.x] += t;
        __syncthreads();
    }
    if (i < n) offs[i] = lds[threadIdx.x] - v;
    if (threadIdx.x == 255) bsums[blockIdx.x] = lds[255];
}

__global__ void scan2_kernel(int* __restrict__ bsums, int* __restrict__ total_out,
                             int nb) {
    __shared__ int lds[256];
    int v = (threadIdx.x < nb) ? bsums[threadIdx.x] : 0;
    lds[threadIdx.x] = v;
    __syncthreads();
    for (int d = 1; d < 256; d <<= 1) {
        int t = (threadIdx.x >= d) ? lds[threadIdx.x - d] : 0;
        __syncthreads();
        lds[threadIdx.x] += t;
        __syncthreads();
    }
    if (threadIdx.x < nb) bsums[threadIdx.x] = lds[threadIdx.x] - v;
    if (threadIdx.x == 255) *total_out = lds[255];
}

__global__ void scan3_kernel(int* __restrict__ arr, const int* __restrict__ bsums,
                             int n) {
    int i = blockIdx.x * 256 + threadIdx.x;
    if (i < n) arr[i] += bsums[blockIdx.x];
}

// ============================================================================
// atomic-free record scatter: 2 edges/thread, high occupancy
// ============================================================================

__global__ void scatter_norank_kernel(const int* __restrict__ ei,
                                      const int* __restrict__ ej,
                                      const float* __restrict__ weights,
                                      const float4* __restrict__ A4,
                                      const float4* __restrict__ B4,
                                      const int* __restrict__ offs,
                                      const ushort* __restrict__ rank,
                                      uint4* __restrict__ rec,
                                      int n_edges) {
    int base = blockIdx.x * (blockDim.x * 2) + threadIdx.x;
    #pragma unroll
    for (int u = 0; u < 2; ++u) {
        int e = base + u * 256;
        if (e >= n_edges) continue;
        int i = ei[e];
        int j = ej[e];
        float we = weights[e];
        int p = offs[i] + (int)rank[e];
        float4 ai = A4[i];
        float4 bj = B4[j];
        float b0 = we / (1.0f + __expf(-(ai.x + bj.x)));
        float b1 = we / (1.0f + __expf(-(ai.y + bj.y)));
        float b2 = we / (1.0f + __expf(-(ai.z + bj.z)));
        float b3 = we / (1.0f + __expf(-(ai.w + bj.w)));
        uint w01 = (uint)__half_as_ushort(__float2half(b0)) |
                   ((uint)__half_as_ushort(__float2half(b1)) << 16);
        uint w23 = (uint)__half_as_ushort(__float2half(b2)) |
                   ((uint)__half_as_ushort(__float2half(b3)) << 16);
        uint4 r;
        r.x = (uint)j; r.y = w01; r.z = w23; r.w = 0u;
        rec[p] = r;
    }
}

// ============================================================================
// gather: exp-free inner loop, 16B broadcast record + fp16 x gather
// ============================================================================

__global__ void gather_rec_kernel(const ushort4* __restrict__ xh4,
                                  const int* __restrict__ offs,
                                  const uint4* __restrict__ rec,
                                  float4* __restrict__ out4) {
    int gid = blockIdx.x * blockDim.x + threadIdx.x;
    int node = gid >> 5;
    int t = threadIdx.x & 31;
    int h = t >> 3;

    int start = offs[node];
    int end = offs[node + 1];
    float4 acc = make_float4(0.f, 0.f, 0.f, 0.f);
    #pragma unroll 4
    for (int k = start; k < end; ++k) {
        uint4 r = rec[k];
        int j = (int)r.x;
        uint wrd = (h < 2) ? r.y : r.z;
        ushort hw = (h & 1) ? (ushort)(wrd >> 16) : (ushort)(wrd & 0xffffu);
        float beta = __half2float(__ushort_as_half(hw));
        ushort4 xv = xh4[j * 32 + t];
        acc.x += __half2float(__ushort_as_half(xv.x)) * beta;
        acc.y += __half2float(__ushort_as_half(xv.y)) * beta;
        acc.z += __half2float(__ushort_as_half(xv.z)) * beta;
        acc.w += __half2float(__ushort_as_half(xv.w)) * beta;
    }
    vfloat4 av; av.x = acc.x; av.y = acc.y; av.z = acc.z; av.w = acc.w;
    __builtin_nontemporal_store(av, (vfloat4*)&out4[node * 32 + t]);
}

// ============================================================================
// v0 ultimate fallback: atomic scatter
// ============================================================================

__global__ void node_dots_kernel(const float* __restrict__ x,
                                 const float* __restrict__ w,
                                 float* __restrict__ ab,
                                 int n_nodes) {
    int gid = blockIdx.x * blockDim.x + threadIdx.x;
    int node = gid >> 7;
    int t = threadIdx.x & 127;
    if (node >= n_nodes) return;
    int h = t >> 5;
    int c = t & 31;
    float xv = x[node * FDIM + t];
    float pa = xv * w[c];
    float pb = xv * w[OUT_CH + c];
    #pragma unroll
    for (int m = 16; m >= 1; m >>= 1) {
        pa += __shfl_xor(pa, m);
        pb += __shfl_xor(pb, m);
    }
    if (c == 0) {
        ab[node * 8 + h * 2 + 0] = pa;
        ab[node * 8 + h * 2 + 1] = pb;
    }
}

__global__ void edge_scatter_kernel(const float* __restrict__ x,
                                    const int* __restrict__ ei_arr,
                                    const int* __restrict__ ej_arr,
                                    const float* __restrict__ weights,
                                    const float* __restrict__ ab,
                                    float* __restrict__ out,
                                    int n_edges) {
    int gid = blockIdx.x * blockDim.x + threadIdx.x;
    int e = gid >> 7;
    int t = threadIdx.x & 127;
    if (e >= n_edges) return;
    int h = t >> 5;
    int i = ei_arr[e];
    int j = ej_arr[e];
    float alpha = ab[i * 8 + h * 2 + 0] + ab[j * 8 + h * 2 + 1];
    float beta = weights[e] / (1.0f + __expf(-alpha));
    atomicAdd(&out[i * FDIM + t], x[j * FDIM + t] * beta);
}

// ============================================================================

extern "C" void kernel_launch(void* const* d_in, const int* in_sizes, int n_in,
                              void* d_out, int out_size, void* d_ws, size_t ws_size,
                              hipStream_t stream) {
    const float* x       = (const float*)d_in[0];
    const int*   eidx    = (const int*)d_in[1];
    const float* weights = (const float*)d_in[2];
    const float* w       = (const float*)d_in[3];
    float* out = (float*)d_out;

    const int* ei_arr = eidx;
    const int* ej_arr = eidx + N_EDGES;

    const int NB = (N_NODES + 255) / 256;  // scan blocks (196)

    // ---- v10 workspace layout ----
    // xh: 12.8MB | A: .8MB | B: .8MB | rec: 12.8MB | rank: 1.6MB |
    // offs: (N+1)*4 | bsums: 1KB | cnt_pad: N*stride*4
    // stride=16 (64B padded) if ws allows (~32.4MB), else stride=1 (~29.3MB)
    {
        char* p = (char*)d_ws;
        ushort4* xh4  = (ushort4*)p;   p += (size_t)N_NODES * FDIM * 2;
        float*   Af   = (float*)p;     p += (size_t)N_NODES * 4 * 4;
        float*   Bf   = (float*)p;     p += (size_t)N_NODES * 4 * 4;
        uint4*   rec  = (uint4*)p;     p += (size_t)N_EDGES * 16;
        ushort*  rank = (ushort*)p;    p += (size_t)N_EDGES * 2;
        int*     offs = (int*)p;       p += (size_t)(N_NODES + 1) * 4;
        int*     bsums= (int*)p;       p += (size_t)256 * 4;
        int*     cnt  = (int*)p;       // strided counters live at the end
        size_t base_need = (size_t)(p - (char*)d_ws);
        size_t need_pad  = base_need + (size_t)N_NODES * 16 * 4;  // shift=4
        size_t need_min  = base_need + (size_t)N_NODES * 4;       // shift=0

        int shift = -1;
        if (ws_size >= need_pad)      shift = 4;
        else if (ws_size >= need_min) shift = 0;

        if (shift >= 0) {
            int n_cnt4 = (N_NODES << shift) / 4;   // int4 words to zero
            prep_kernel<<<(N_NODES * 32) / 256, 256, 0, stream>>>(
                (const float4*)x, w, Af, Bf, xh4, (int4*)cnt, n_cnt4);
            hist_rank_kernel<<<(N_EDGES + 511) / 512, 256, 0, stream>>>(
                ei_arr, cnt, rank, N_EDGES, shift);
            scan1_kernel<<<NB, 256, 0, stream>>>(cnt, offs, bsums, N_NODES, shift);
            scan2_kernel<<<1, 256, 0, stream>>>(bsums, offs + N_NODES, NB);
            scan3_kernel<<<NB, 256, 0, stream>>>(offs, bsums, N_NODES);
            scatter_norank_kernel<<<(N_EDGES + 511) / 512, 256, 0, stream>>>(
                ei_arr, ej_arr, weights, (const float4*)Af, (const float4*)Bf,
                offs, rank, rec, N_EDGES);
            gather_rec_kernel<<<(N_NODES * 32) / 256, 256, 0, stream>>>(
                xh4, offs, rec, (float4*)out);
            return;
        }
    }

    // ---- v0 atomic fallback ----
    {
        float* ab = (float*)d_ws;  // 1.6MB
        int grid = (N_NODES * FDIM + 255) / 256;
        node_dots_kernel<<<grid, 256, 0, stream>>>(x, w, ab, N_NODES);
        hipMemsetAsync(d_out, 0, (size_t)out_size * sizeof(float), stream);
        long long threads_total = (long long)N_EDGES * FDIM;
        long long g = (threads_total + 255) / 256;
        edge_scatter_kernel<<<(int)g, 256, 0, stream>>>(
            x, ei_arr, ej_arr, weights, ab, out, N_EDGES);
    }
}